// Round 13
// baseline (203.086 us; speedup 1.0000x reference)
//
#include <hip/hip_runtime.h>

// GNB dispersion — Round 20: R19 base + 8-wide accum gather batching + scatter
// cn-atomics moved past the barrier.
// R19 (195.7us record): scatter 62 / accum ~50 / launches ~70. Both kernels
// latency-bound with idle pipes. (1) accum loop widened to 8 records/iter ->
// 8 outstanding P2[s] gathers per thread (2x MLP). (2) scatter's fused-degree
// global atomics issued AFTER the reserve barrier so their ~900cy completion
// drains at wave exit, not at the mid-block __syncthreads vmcnt(0).
//   init -> scatter(+degree) -> params -> accum -> reduce
// Record: uint2{ s | rlow<<17, len_bits }.
// ws (words): [cursor 128][cntrs 8][cn cnw][P2 2n][isCN nwp]
//             [rep NB2*ES*1024][ovrec uint4 ocap][buckets uint2 NB2*cap]

#define B2SHIFT 10
#define B2SIZE  1024
#define TILE    4096
#define SBLK    512
#define ESLICES 16
#define MAXB    128
#define AREP    2
#define BLK     256

__device__ __constant__ float2 GNB_RC6[87] = {
    {0.f, 0.f},
    {3.6516f, 95.99f},   {2.1843f, 40.67f},   {1.2711f, 70.21f},
    {3.3497f, 114.51f},  {2.7079f, 152.36f},  {1.8219f, 184.28f},
    {2.4667f, 482.54f},  {2.365f, 405.57f},   {1.5062f, 218.45f},
    {1.8233f, 174.81f},  {1.3974f, 181.7f},   {3.3515f, 263.02f},
    {3.0102f, 228.1f},   {3.1629f, 359.43f},  {3.2554f, 3222.12f},
    {2.9539f, 2144.49f}, {3.0368f, 2072.46f}, {2.6598f, 1357.42f},
    {4.0877f, 1406.65f}, {4.1275f, 1058.36f}, {9.7282f, 11498.73f},
    {8.5322f, 3361.33f}, {7.2344f, 2095.91f}, {5.3605f, 1049.31f},
    {3.718f, 966.27f},   {3.6408f, 1571.36f}, {3.4961f, 1183.59f},
    {3.5108f, 787.76f},  {3.0537f, 563.93f},  {3.0261f, 592.91f},
    {3.1735f, 430.82f},  {3.1773f, 812.57f},  {3.8357f, 4533.53f},
    {3.1109f, 3440.92f}, {3.2122f, 3859.82f}, {2.8263f, 2729.6f},
    {2.412f, 1864.19f},  {1.894f, 1175.73f},  {11.2061f, 32141.18f},
    {6.821f, 27655.14f}, {7.2367f, 2864.2f},  {3.901f, 3563.45f},
    {4.0857f, 3266.43f}, {4.045f, 3967.23f},  {3.4813f, 2233.82f},
    {3.0487f, 1393.49f}, {2.7795f, 1315.09f}, {2.8673f, 1311.47f},
    {3.3339f, 1460.56f}, {3.0086f, 1662.99f}, {3.9919f, 8089.97f},
    {3.4209f, 6887.05f}, {3.5649f, 8799.32f}, {3.0288f, 6136.5f},
    {2.262f, 3757.31f},  {1.3837f, 2561.18f}, {12.171f, 66580.83f},
    {0.f,0.f},{0.f,0.f},{0.f,0.f},{0.f,0.f},{0.f,0.f},{0.f,0.f},{0.f,0.f},
    {0.f,0.f},{0.f,0.f},{0.f,0.f},{0.f,0.f},{0.f,0.f},{0.f,0.f},{0.f,0.f},
    {6.0791f, 27593.76f}, {5.7661f, 15364.65f}, {3.6366f, 2734.5f},
    {4.241f, 4801.82f},   {4.1348f, 5685.94f},  {3.4213f, 2786.0f},
    {3.2486f, 2699.79f},  {2.9588f, 2282.6f},   {2.9381f, 2476.79f},
    {2.7711f, 2988.7f},   {2.5816f, 2506.63f},  {3.785f, 8916.84f},
    {3.5381f, 8694.22f},  {3.6985f, 11821.61f}, {3.0551f, 8410.64f},
};

// Zero [cursor|cntrs|cn] (contiguous at ws start) + build isCN bitmask.
__global__ void gnb_init(const int* __restrict__ Z, unsigned* __restrict__ isCN,
                         int nw, int n_nodes, int4* __restrict__ zp4, int zq,
                         int* __restrict__ zp, int zwords) {
    int stride = gridDim.x * blockDim.x;
    int t0 = blockIdx.x * blockDim.x + threadIdx.x;
    int4 z4 = make_int4(0, 0, 0, 0);
    for (int i = t0; i < zq; i += stride) zp4[i] = z4;
    for (int i = zq * 4 + t0; i < zwords; i += stride) zp[i] = 0;
    for (int w = t0; w < nw; w += stride) {
        unsigned m = 0;
        int base = w << 5;
        int lim = n_nodes - base; if (lim > 32) lim = 32;
        for (int k = 0; k < lim; ++k) {
            int z = Z[base + k];
            if (z == 6 || z == 7) m |= (1u << k);
        }
        isCN[w] = m;
    }
}

__global__ void gnb_params(const int* __restrict__ Z, const int* __restrict__ cn,
                           float2* __restrict__ P2, int n_nodes) {
    int i = blockIdx.x * blockDim.x + threadIdx.x;
    if (i >= n_nodes) return;
    int z = Z[i];
    float Rp, C6;
    if (z == 6) {
        if (cn[i] <= 3) { Rp = 2.2348f; C6 = 429.69f; }
        else            { Rp = 1.8219f; C6 = 184.28f; }
    } else if (z == 7) {
        if (cn[i] <= 2) { Rp = 2.6454f; C6 = 720.18f; }
        else            { Rp = 2.4667f; C6 = 482.54f; }
    } else {
        float2 rc = GNB_RC6[z];
        Rp = rc.x; C6 = rc.y;
    }
    P2[i] = make_float2(sqrtf(C6), sqrtf(sqrtf(Rp)));
}

__device__ __forceinline__ float gnb_energy_eval(float2 ps, float2 pr, float rlen) {
    float env;
    if (rlen < 8.0f) {
        env = 1.0f;
    } else {
        float x = (rlen - 8.0f) * 0.5f;          // kept edges guarantee x < 1
        float x2 = x * x;
        float x6 = x2 * x2 * x2;
        env = 1.0f - 28.0f * x6 + 48.0f * x6 * x - 21.0f * x6 * x2;
    }
    float sR  = ps.y * pr.y;                     // sqrt(R_ij)
    float C6  = ps.x * pr.x;                     // sqrt(C6_s*C6_r)
    float Rij = sR * sR;
    float R3  = Rij * Rij * Rij;
    float R6  = R3 * R3;
    float r0  = 0.4f * sR + 4.0f;
    float t   = r0 / rlen;
    float t2 = t * t, t4 = t2 * t2, t8 = t4 * t4;
    float t14 = t8 * t4 * t2;
    float fd = 1.0f / (1.0f + 6.0f * t14);
    float rl2 = rlen * rlen;
    float r6 = rl2 * rl2 * rl2;
    return -0.5f * C6 / (R6 + r6) * fd * env;
}

// Gather-free scatter; fused-degree atomics issued in the store phase so their
// completion drains at wave exit instead of the mid-block barrier.
__global__ void __launch_bounds__(SBLK)
gnb_scatter(const int* __restrict__ send, const int* __restrict__ recv,
            const float* __restrict__ len, const unsigned* __restrict__ isCN,
            int* __restrict__ cn,
            uint2* __restrict__ buckets, unsigned* __restrict__ cursor,
            uint4* __restrict__ ovrec, unsigned* __restrict__ ocur,
            int n_edges, unsigned cap, unsigned ocap) {
    __shared__ unsigned hist[MAXB];
    __shared__ unsigned gbase[MAXB];
    const int tid = threadIdx.x;
    const int e0  = blockIdx.x * TILE;

    if (tid < MAXB) hist[tid] = 0;
    __syncthreads();

    unsigned ss[8]; unsigned rr[8]; float ll[8];
    const bool full = (e0 + TILE <= n_edges);
    if (full) {
        int4   sv0 = *(const int4*)(send + e0 + tid * 4);
        int4   rv0 = *(const int4*)(recv + e0 + tid * 4);
        float4 lv0 = *(const float4*)(len + e0 + tid * 4);
        int4   sv1 = *(const int4*)(send + e0 + 2048 + tid * 4);
        int4   rv1 = *(const int4*)(recv + e0 + 2048 + tid * 4);
        float4 lv1 = *(const float4*)(len + e0 + 2048 + tid * 4);
        ss[0]=(unsigned)sv0.x; ss[1]=(unsigned)sv0.y; ss[2]=(unsigned)sv0.z; ss[3]=(unsigned)sv0.w;
        ss[4]=(unsigned)sv1.x; ss[5]=(unsigned)sv1.y; ss[6]=(unsigned)sv1.z; ss[7]=(unsigned)sv1.w;
        rr[0]=(unsigned)rv0.x; rr[1]=(unsigned)rv0.y; rr[2]=(unsigned)rv0.z; rr[3]=(unsigned)rv0.w;
        rr[4]=(unsigned)rv1.x; rr[5]=(unsigned)rv1.y; rr[6]=(unsigned)rv1.z; rr[7]=(unsigned)rv1.w;
        ll[0]=lv0.x; ll[1]=lv0.y; ll[2]=lv0.z; ll[3]=lv0.w;
        ll[4]=lv1.x; ll[5]=lv1.y; ll[6]=lv1.z; ll[7]=lv1.w;
    } else {
        #pragma unroll
        for (int i = 0; i < 8; ++i) {
            int e = e0 + ((i >> 2) * 2048) + tid * 4 + (i & 3);
            bool ok = (e < n_edges);
            ss[i] = ok ? (unsigned)send[e] : 0u;
            rr[i] = ok ? (unsigned)recv[e] : 0u;
            ll[i] = ok ? len[e] : 1.0e9f;
        }
    }

    unsigned bk[8];
    #pragma unroll
    for (int i = 0; i < 8; ++i) {
        if (ll[i] < 10.0f) {
            unsigned b   = rr[i] >> B2SHIFT;
            unsigned off = atomicAdd(&hist[b], 1u);
            bk[i] = b | (off << 7);
        } else {
            bk[i] = 0x80000000u;
        }
    }
    __syncthreads();

    if (tid < MAXB) {
        unsigned c = hist[tid];
        gbase[tid] = c ? atomicAdd(&cursor[tid], c) : 0u;
    }
    __syncthreads();

    // store phase: record stores + fused-degree atomics (drain at wave exit)
    #pragma unroll
    for (int i = 0; i < 8; ++i) {
        unsigned bo = bk[i];
        if (!(bo & 0x80000000u)) {
            unsigned b = bo & (MAXB - 1);
            unsigned g = gbase[b] + (bo >> 7);
            unsigned x = ss[i] | ((rr[i] & (B2SIZE - 1)) << 17);
            if (g < cap) {
                buckets[(size_t)b * cap + g] = make_uint2(x, __float_as_uint(ll[i]));
            } else {
                unsigned o = atomicAdd(ocur, 1u);
                if (o < ocap)
                    ovrec[o] = make_uint4(rr[i], ss[i], __float_as_uint(ll[i]), 0u);
            }
        }
    }
    #pragma unroll
    for (int i = 0; i < 8; ++i) {
        if (ll[i] < 1.0e8f && ((isCN[rr[i] >> 5] >> (rr[i] & 31)) & 1u))
            atomicAdd(&cn[rr[i]], 1);
    }
}

// Accum: stage bucket P2 in LDS, stream records 8/thread/iter (4x uint4),
// 8 batched P2[s] gathers, eval, LDS add (2 replicas).
__global__ void __launch_bounds__(BLK)
gnb_accum(const uint2* __restrict__ buckets, const unsigned* __restrict__ cursor,
          const uint4* __restrict__ ovrec, const unsigned* __restrict__ ocur,
          const float2* __restrict__ P2, float* __restrict__ rep,
          unsigned cap, unsigned ocap, int n_nodes) {
    __shared__ float  acc[AREP][B2SIZE + 8];
    __shared__ float2 p2loc[B2SIZE];
    const int b   = blockIdx.x >> 4;             // ESLICES == 16
    const int sl  = blockIdx.x & (ESLICES - 1);
    const int tid = threadIdx.x;
    const int rp  = (tid >> 6) & (AREP - 1);

    for (int i = tid; i < AREP * (B2SIZE + 8); i += BLK) acc[0][i] = 0.0f;
    for (int i = tid; i < B2SIZE; i += BLK) {
        int node = (b << B2SHIFT) + i;
        p2loc[i] = (node < n_nodes) ? P2[node] : make_float2(0.f, 0.f);
    }
    __syncthreads();

    if (sl == 0) {                    // overflow fold first (usually empty)
        unsigned n = *ocur; if (n > ocap) n = ocap;
        for (unsigned i = tid; i < n; i += BLK) {
            uint4 rc = ovrec[i];
            if ((rc.x >> B2SHIFT) == (unsigned)b) {
                float e = gnb_energy_eval(P2[rc.y], p2loc[rc.x & (B2SIZE - 1)],
                                          __uint_as_float(rc.z));
                atomicAdd(&acc[rp][rc.x & (B2SIZE - 1)], e);
            }
        }
    }

    unsigned count = cursor[b];
    if (count > cap) count = cap;
    unsigned seg = (((count + ESLICES - 1) / ESLICES) + 7u) & ~7u;   // 8-rec aligned
    unsigned st  = (unsigned)sl * seg; if (st > count) st = count;
    unsigned en  = st + seg; if (en > count) en = count;

    const uint2* src = buckets + (size_t)b * cap;
    for (unsigned i = st + tid * 8; i < en; i += BLK * 8) {
        if (i + 8 <= en) {
            uint4 q0 = *(const uint4*)(src + i);
            uint4 q1 = *(const uint4*)(src + i + 2);
            uint4 q2 = *(const uint4*)(src + i + 4);
            uint4 q3 = *(const uint4*)(src + i + 6);
            unsigned sx[8] = {q0.x, q0.z, q1.x, q1.z, q2.x, q2.z, q3.x, q3.z};
            unsigned lb[8] = {q0.y, q0.w, q1.y, q1.w, q2.y, q2.w, q3.y, q3.w};
            float2 ps[8];
            #pragma unroll
            for (int j = 0; j < 8; ++j) ps[j] = P2[sx[j] & 0x1FFFFu];   // 8 in flight
            #pragma unroll
            for (int j = 0; j < 8; ++j) {
                unsigned rlow = (sx[j] >> 17) & (B2SIZE - 1);
                float e = gnb_energy_eval(ps[j], p2loc[rlow], __uint_as_float(lb[j]));
                atomicAdd(&acc[rp][rlow], e);
            }
        } else {
            for (unsigned q = i; q < en; ++q) {
                uint2 rec = src[q];
                unsigned rlow = (rec.x >> 17) & (B2SIZE - 1);
                float e = gnb_energy_eval(P2[rec.x & 0x1FFFFu], p2loc[rlow],
                                          __uint_as_float(rec.y));
                atomicAdd(&acc[rp][rlow], e);
            }
        }
    }
    __syncthreads();

    float* dst = rep + (size_t)blockIdx.x * B2SIZE;
    for (int i = tid; i < B2SIZE; i += BLK)
        dst[i] = acc[0][i] + acc[1][i];
}

__global__ void gnb_reduce(const float* __restrict__ rep, float* __restrict__ out,
                           int n_nodes) {
    int i = blockIdx.x * blockDim.x + threadIdx.x;
    if (i >= n_nodes) return;
    int b = i >> B2SHIFT;
    int j = i & (B2SIZE - 1);
    const float* src = rep + ((size_t)b * ESLICES) * B2SIZE + j;
    float sum = 0.0f;
    #pragma unroll
    for (int s = 0; s < ESLICES; ++s) sum += src[(size_t)s * B2SIZE];
    out[i] = sum;
}

extern "C" void kernel_launch(void* const* d_in, const int* in_sizes, int n_in,
                              void* d_out, int out_size, void* d_ws, size_t ws_size,
                              hipStream_t stream) {
    const int*   Z    = (const int*)d_in[0];
    const int*   eidx = (const int*)d_in[1];
    const float* len  = (const float*)d_in[2];
    float*       out  = (float*)d_out;

    const int n_nodes = in_sizes[0];
    const int n_edges = in_sizes[2];
    const int* send = eidx;
    const int* recv = eidx + n_edges;

    const int NB2 = (n_nodes + B2SIZE - 1) >> B2SHIFT;   // 98 for n=100000
    const int nw  = (n_nodes + 31) >> 5;
    const int nwp = (nw + 7) & ~7;
    const int cnw = (n_nodes + 3) & ~3;                  // cn slot, 16B-aligned

    // ws layout (words): [cursor 128][cntrs 8][cn cnw][P2 2n][isCN nwp][rep][tail]
    char* ws = (char*)d_ws;
    unsigned* cursor = (unsigned*)ws;                                            // 128
    unsigned* cntrs  = (unsigned*)(ws + MAXB * 4);                               // 8
    int*      cn     = (int*)(ws + (MAXB + 8) * 4);                              // cnw
    float2*   P2     = (float2*)(ws + ((size_t)cnw + MAXB + 8) * 4);             // 2n
    unsigned* isCN   = (unsigned*)(ws + ((size_t)cnw + 2 * (size_t)n_nodes
                                         + MAXB + 8) * 4);                       // nwp
    float*    rep    = (float*)((char*)isCN + (size_t)nwp * 4);
    size_t rep_w     = (size_t)NB2 * ESLICES * B2SIZE;
    char*     tail   = (char*)rep + rep_w * 4;

    size_t fixed_words = (size_t)cnw + 2 * (size_t)n_nodes + MAXB + 8
                         + nwp + rep_w;
    size_t total_words = ws_size / 4;
    size_t avail = total_words > fixed_words ? total_words - fixed_words : 0;
    size_t ovw = avail / 64;                      // ~1.5% to overflow queue
    unsigned ocap = (unsigned)(ovw / 4);          // uint4 records
    size_t capw = (avail - ovw) / (size_t)NB2;    // words per bucket
    long cap = (long)((capw / 2) & ~(size_t)7);   // uint2 records, 8-rec aligned
    if (cap > n_edges) cap = (n_edges + 7) & ~7;
    if (cap < 0) cap = 0;
    uint4* ovrec   = (uint4*)tail;
    uint2* buckets = (uint2*)(tail + (size_t)ocap * 16);

    const int B = 256;
    int node_blocks = (n_nodes + B - 1) / B;
    int scat_blocks = (n_edges + TILE - 1) / TILE;
    int nunits      = NB2 * ESLICES;
    int zero_words  = cnw + MAXB + 8;             // cursor + cntrs + cn
    int zq = zero_words / 4;

    gnb_init<<<256, B, 0, stream>>>(Z, isCN, nw, n_nodes, (int4*)ws, zq,
                                    (int*)ws, zero_words);
    gnb_scatter<<<scat_blocks, SBLK, 0, stream>>>(send, recv, len, isCN, cn,
                                                  buckets, cursor, ovrec, cntrs,
                                                  n_edges, (unsigned)cap, ocap);
    gnb_params<<<node_blocks, B, 0, stream>>>(Z, cn, P2, n_nodes);
    gnb_accum<<<nunits, BLK, 0, stream>>>(buckets, cursor, ovrec, cntrs,
                                          P2, rep, (unsigned)cap, ocap, n_nodes);
    gnb_reduce<<<node_blocks, B, 0, stream>>>(rep, out, n_nodes);
}

// Round 14
// 196.712 us; speedup vs baseline: 1.0324x; 1.0324x over previous
//
#include <hip/hip_runtime.h>

// GNB dispersion — Round 21: revert to R19 verbatim (195.7us record).
// R20 post-mortem: both micro-levers regressed (scatter cn-atomics-after-barrier
// 62->66us: 16 VMEM ops in one end-of-wave drain window vs overlapped with the
// barrier wait; accum 8-wide: null at 32 waves/CU — TLP already saturates the
// gather pipe). Component ledger (best of all measured variants):
//   launches 5 x ~14us = 70 (fusions measured worse: grid.sync +150us/sync,
//   threadfence +200us) | scatter 62 (best of 7 variants) | accum ~47 (best of
//   3) | init+params+reduce ~9. Floor ~188us; R19 measured 195.7 (within 4%).
//   init -> scatter(+degree) -> params -> accum -> reduce
// Record: uint2{ s | rlow<<17, len_bits }.
// ws (words): [cursor 128][cntrs 8][cn cnw][P2 2n][isCN nwp]
//             [rep NB2*ES*1024][ovrec uint4 ocap][buckets uint2 NB2*cap]

#define B2SHIFT 10
#define B2SIZE  1024
#define TILE    4096
#define SBLK    512
#define ESLICES 16
#define MAXB    128
#define AREP    2
#define BLK     256

__device__ __constant__ float2 GNB_RC6[87] = {
    {0.f, 0.f},
    {3.6516f, 95.99f},   {2.1843f, 40.67f},   {1.2711f, 70.21f},
    {3.3497f, 114.51f},  {2.7079f, 152.36f},  {1.8219f, 184.28f},
    {2.4667f, 482.54f},  {2.365f, 405.57f},   {1.5062f, 218.45f},
    {1.8233f, 174.81f},  {1.3974f, 181.7f},   {3.3515f, 263.02f},
    {3.0102f, 228.1f},   {3.1629f, 359.43f},  {3.2554f, 3222.12f},
    {2.9539f, 2144.49f}, {3.0368f, 2072.46f}, {2.6598f, 1357.42f},
    {4.0877f, 1406.65f}, {4.1275f, 1058.36f}, {9.7282f, 11498.73f},
    {8.5322f, 3361.33f}, {7.2344f, 2095.91f}, {5.3605f, 1049.31f},
    {3.718f, 966.27f},   {3.6408f, 1571.36f}, {3.4961f, 1183.59f},
    {3.5108f, 787.76f},  {3.0537f, 563.93f},  {3.0261f, 592.91f},
    {3.1735f, 430.82f},  {3.1773f, 812.57f},  {3.8357f, 4533.53f},
    {3.1109f, 3440.92f}, {3.2122f, 3859.82f}, {2.8263f, 2729.6f},
    {2.412f, 1864.19f},  {1.894f, 1175.73f},  {11.2061f, 32141.18f},
    {6.821f, 27655.14f}, {7.2367f, 2864.2f},  {3.901f, 3563.45f},
    {4.0857f, 3266.43f}, {4.045f, 3967.23f},  {3.4813f, 2233.82f},
    {3.0487f, 1393.49f}, {2.7795f, 1315.09f}, {2.8673f, 1311.47f},
    {3.3339f, 1460.56f}, {3.0086f, 1662.99f}, {3.9919f, 8089.97f},
    {3.4209f, 6887.05f}, {3.5649f, 8799.32f}, {3.0288f, 6136.5f},
    {2.262f, 3757.31f},  {1.3837f, 2561.18f}, {12.171f, 66580.83f},
    {0.f,0.f},{0.f,0.f},{0.f,0.f},{0.f,0.f},{0.f,0.f},{0.f,0.f},{0.f,0.f},
    {0.f,0.f},{0.f,0.f},{0.f,0.f},{0.f,0.f},{0.f,0.f},{0.f,0.f},{0.f,0.f},
    {6.0791f, 27593.76f}, {5.7661f, 15364.65f}, {3.6366f, 2734.5f},
    {4.241f, 4801.82f},   {4.1348f, 5685.94f},  {3.4213f, 2786.0f},
    {3.2486f, 2699.79f},  {2.9588f, 2282.6f},   {2.9381f, 2476.79f},
    {2.7711f, 2988.7f},   {2.5816f, 2506.63f},  {3.785f, 8916.84f},
    {3.5381f, 8694.22f},  {3.6985f, 11821.61f}, {3.0551f, 8410.64f},
};

// Zero [cursor|cntrs|cn] (contiguous at ws start) + build isCN bitmask.
__global__ void gnb_init(const int* __restrict__ Z, unsigned* __restrict__ isCN,
                         int nw, int n_nodes, int4* __restrict__ zp4, int zq,
                         int* __restrict__ zp, int zwords) {
    int stride = gridDim.x * blockDim.x;
    int t0 = blockIdx.x * blockDim.x + threadIdx.x;
    int4 z4 = make_int4(0, 0, 0, 0);
    for (int i = t0; i < zq; i += stride) zp4[i] = z4;
    for (int i = zq * 4 + t0; i < zwords; i += stride) zp[i] = 0;
    for (int w = t0; w < nw; w += stride) {
        unsigned m = 0;
        int base = w << 5;
        int lim = n_nodes - base; if (lim > 32) lim = 32;
        for (int k = 0; k < lim; ++k) {
            int z = Z[base + k];
            if (z == 6 || z == 7) m |= (1u << k);
        }
        isCN[w] = m;
    }
}

__global__ void gnb_params(const int* __restrict__ Z, const int* __restrict__ cn,
                           float2* __restrict__ P2, int n_nodes) {
    int i = blockIdx.x * blockDim.x + threadIdx.x;
    if (i >= n_nodes) return;
    int z = Z[i];
    float Rp, C6;
    if (z == 6) {
        if (cn[i] <= 3) { Rp = 2.2348f; C6 = 429.69f; }
        else            { Rp = 1.8219f; C6 = 184.28f; }
    } else if (z == 7) {
        if (cn[i] <= 2) { Rp = 2.6454f; C6 = 720.18f; }
        else            { Rp = 2.4667f; C6 = 482.54f; }
    } else {
        float2 rc = GNB_RC6[z];
        Rp = rc.x; C6 = rc.y;
    }
    P2[i] = make_float2(sqrtf(C6), sqrtf(sqrtf(Rp)));
}

__device__ __forceinline__ float gnb_energy_eval(float2 ps, float2 pr, float rlen) {
    float env;
    if (rlen < 8.0f) {
        env = 1.0f;
    } else {
        float x = (rlen - 8.0f) * 0.5f;          // kept edges guarantee x < 1
        float x2 = x * x;
        float x6 = x2 * x2 * x2;
        env = 1.0f - 28.0f * x6 + 48.0f * x6 * x - 21.0f * x6 * x2;
    }
    float sR  = ps.y * pr.y;                     // sqrt(R_ij)
    float C6  = ps.x * pr.x;                     // sqrt(C6_s*C6_r)
    float Rij = sR * sR;
    float R3  = Rij * Rij * Rij;
    float R6  = R3 * R3;
    float r0  = 0.4f * sR + 4.0f;
    float t   = r0 / rlen;
    float t2 = t * t, t4 = t2 * t2, t8 = t4 * t4;
    float t14 = t8 * t4 * t2;
    float fd = 1.0f / (1.0f + 6.0f * t14);
    float rl2 = rlen * rlen;
    float r6 = rl2 * rl2 * rl2;
    return -0.5f * C6 / (R6 + r6) * fd * env;
}

// Gather-free scatter (+fused degree): R16/R19 form — cn atomics BEFORE the
// reserve barrier (overlap the histogram wait; R20 measured the alternative worse).
__global__ void __launch_bounds__(SBLK)
gnb_scatter(const int* __restrict__ send, const int* __restrict__ recv,
            const float* __restrict__ len, const unsigned* __restrict__ isCN,
            int* __restrict__ cn,
            uint2* __restrict__ buckets, unsigned* __restrict__ cursor,
            uint4* __restrict__ ovrec, unsigned* __restrict__ ocur,
            int n_edges, unsigned cap, unsigned ocap) {
    __shared__ unsigned hist[MAXB];
    __shared__ unsigned gbase[MAXB];
    const int tid = threadIdx.x;
    const int e0  = blockIdx.x * TILE;

    if (tid < MAXB) hist[tid] = 0;
    __syncthreads();

    unsigned ss[8]; unsigned rr[8]; float ll[8];
    const bool full = (e0 + TILE <= n_edges);
    if (full) {
        int4   sv0 = *(const int4*)(send + e0 + tid * 4);
        int4   rv0 = *(const int4*)(recv + e0 + tid * 4);
        float4 lv0 = *(const float4*)(len + e0 + tid * 4);
        int4   sv1 = *(const int4*)(send + e0 + 2048 + tid * 4);
        int4   rv1 = *(const int4*)(recv + e0 + 2048 + tid * 4);
        float4 lv1 = *(const float4*)(len + e0 + 2048 + tid * 4);
        ss[0]=(unsigned)sv0.x; ss[1]=(unsigned)sv0.y; ss[2]=(unsigned)sv0.z; ss[3]=(unsigned)sv0.w;
        ss[4]=(unsigned)sv1.x; ss[5]=(unsigned)sv1.y; ss[6]=(unsigned)sv1.z; ss[7]=(unsigned)sv1.w;
        rr[0]=(unsigned)rv0.x; rr[1]=(unsigned)rv0.y; rr[2]=(unsigned)rv0.z; rr[3]=(unsigned)rv0.w;
        rr[4]=(unsigned)rv1.x; rr[5]=(unsigned)rv1.y; rr[6]=(unsigned)rv1.z; rr[7]=(unsigned)rv1.w;
        ll[0]=lv0.x; ll[1]=lv0.y; ll[2]=lv0.z; ll[3]=lv0.w;
        ll[4]=lv1.x; ll[5]=lv1.y; ll[6]=lv1.z; ll[7]=lv1.w;
    } else {
        #pragma unroll
        for (int i = 0; i < 8; ++i) {
            int e = e0 + ((i >> 2) * 2048) + tid * 4 + (i & 3);
            bool ok = (e < n_edges);
            ss[i] = ok ? (unsigned)send[e] : 0u;
            rr[i] = ok ? (unsigned)recv[e] : 0u;
            ll[i] = ok ? len[e] : 1.0e9f;
        }
    }

    // fused degree: ALL edges, isCN-filtered (~2.3% fire), fire-and-forget
    #pragma unroll
    for (int i = 0; i < 8; ++i) {
        if (ll[i] < 1.0e8f && ((isCN[rr[i] >> 5] >> (rr[i] & 31)) & 1u))
            atomicAdd(&cn[rr[i]], 1);
    }

    unsigned bk[8];
    #pragma unroll
    for (int i = 0; i < 8; ++i) {
        if (ll[i] < 10.0f) {
            unsigned b   = rr[i] >> B2SHIFT;
            unsigned off = atomicAdd(&hist[b], 1u);
            bk[i] = b | (off << 7);
        } else {
            bk[i] = 0x80000000u;
        }
    }
    __syncthreads();

    if (tid < MAXB) {
        unsigned c = hist[tid];
        gbase[tid] = c ? atomicAdd(&cursor[tid], c) : 0u;
    }
    __syncthreads();

    #pragma unroll
    for (int i = 0; i < 8; ++i) {
        unsigned bo = bk[i];
        if (!(bo & 0x80000000u)) {
            unsigned b = bo & (MAXB - 1);
            unsigned g = gbase[b] + (bo >> 7);
            unsigned x = ss[i] | ((rr[i] & (B2SIZE - 1)) << 17);
            if (g < cap) {
                buckets[(size_t)b * cap + g] = make_uint2(x, __float_as_uint(ll[i]));
            } else {
                unsigned o = atomicAdd(ocur, 1u);
                if (o < ocap)
                    ovrec[o] = make_uint4(rr[i], ss[i], __float_as_uint(ll[i]), 0u);
            }
        }
    }
}

// Accum: stage bucket P2 in LDS, stream records 4/thread/iter, gather P2[s],
// eval, LDS add (2 replicas). No fence — reduce is a separate kernel.
__global__ void __launch_bounds__(BLK)
gnb_accum(const uint2* __restrict__ buckets, const unsigned* __restrict__ cursor,
          const uint4* __restrict__ ovrec, const unsigned* __restrict__ ocur,
          const float2* __restrict__ P2, float* __restrict__ rep,
          unsigned cap, unsigned ocap, int n_nodes) {
    __shared__ float  acc[AREP][B2SIZE + 8];
    __shared__ float2 p2loc[B2SIZE];
    const int b   = blockIdx.x >> 4;             // ESLICES == 16
    const int sl  = blockIdx.x & (ESLICES - 1);
    const int tid = threadIdx.x;
    const int rp  = (tid >> 6) & (AREP - 1);

    for (int i = tid; i < AREP * (B2SIZE + 8); i += BLK) acc[0][i] = 0.0f;
    for (int i = tid; i < B2SIZE; i += BLK) {
        int node = (b << B2SHIFT) + i;
        p2loc[i] = (node < n_nodes) ? P2[node] : make_float2(0.f, 0.f);
    }
    __syncthreads();

    if (sl == 0) {                    // overflow fold first (usually empty)
        unsigned n = *ocur; if (n > ocap) n = ocap;
        for (unsigned i = tid; i < n; i += BLK) {
            uint4 rc = ovrec[i];
            if ((rc.x >> B2SHIFT) == (unsigned)b) {
                float e = gnb_energy_eval(P2[rc.y], p2loc[rc.x & (B2SIZE - 1)],
                                          __uint_as_float(rc.z));
                atomicAdd(&acc[rp][rc.x & (B2SIZE - 1)], e);
            }
        }
    }

    unsigned count = cursor[b];
    if (count > cap) count = cap;
    unsigned seg = (((count + ESLICES - 1) / ESLICES) + 3u) & ~3u;   // 4-rec aligned
    unsigned st  = (unsigned)sl * seg; if (st > count) st = count;
    unsigned en  = st + seg; if (en > count) en = count;

    const uint2* src = buckets + (size_t)b * cap;
    for (unsigned i = st + tid * 4; i < en; i += BLK * 4) {
        if (i + 4 <= en) {
            uint4 q0 = *(const uint4*)(src + i);
            uint4 q1 = *(const uint4*)(src + i + 2);
            unsigned sx[4] = {q0.x, q0.z, q1.x, q1.z};
            unsigned lb[4] = {q0.y, q0.w, q1.y, q1.w};
            float2 ps[4];
            #pragma unroll
            for (int j = 0; j < 4; ++j) ps[j] = P2[sx[j] & 0x1FFFFu];
            #pragma unroll
            for (int j = 0; j < 4; ++j) {
                unsigned rlow = (sx[j] >> 17) & (B2SIZE - 1);
                float e = gnb_energy_eval(ps[j], p2loc[rlow], __uint_as_float(lb[j]));
                atomicAdd(&acc[rp][rlow], e);
            }
        } else {
            for (unsigned q = i; q < en; ++q) {
                uint2 rec = src[q];
                unsigned rlow = (rec.x >> 17) & (B2SIZE - 1);
                float e = gnb_energy_eval(P2[rec.x & 0x1FFFFu], p2loc[rlow],
                                          __uint_as_float(rec.y));
                atomicAdd(&acc[rp][rlow], e);
            }
        }
    }
    __syncthreads();

    float* dst = rep + (size_t)blockIdx.x * B2SIZE;
    for (int i = tid; i < B2SIZE; i += BLK)
        dst[i] = acc[0][i] + acc[1][i];
}

__global__ void gnb_reduce(const float* __restrict__ rep, float* __restrict__ out,
                           int n_nodes) {
    int i = blockIdx.x * blockDim.x + threadIdx.x;
    if (i >= n_nodes) return;
    int b = i >> B2SHIFT;
    int j = i & (B2SIZE - 1);
    const float* src = rep + ((size_t)b * ESLICES) * B2SIZE + j;
    float sum = 0.0f;
    #pragma unroll
    for (int s = 0; s < ESLICES; ++s) sum += src[(size_t)s * B2SIZE];
    out[i] = sum;
}

extern "C" void kernel_launch(void* const* d_in, const int* in_sizes, int n_in,
                              void* d_out, int out_size, void* d_ws, size_t ws_size,
                              hipStream_t stream) {
    const int*   Z    = (const int*)d_in[0];
    const int*   eidx = (const int*)d_in[1];
    const float* len  = (const float*)d_in[2];
    float*       out  = (float*)d_out;

    const int n_nodes = in_sizes[0];
    const int n_edges = in_sizes[2];
    const int* send = eidx;
    const int* recv = eidx + n_edges;

    const int NB2 = (n_nodes + B2SIZE - 1) >> B2SHIFT;   // 98 for n=100000
    const int nw  = (n_nodes + 31) >> 5;
    const int nwp = (nw + 7) & ~7;
    const int cnw = (n_nodes + 3) & ~3;                  // cn slot, 16B-aligned

    // ws layout (words): [cursor 128][cntrs 8][cn cnw][P2 2n][isCN nwp][rep][tail]
    char* ws = (char*)d_ws;
    unsigned* cursor = (unsigned*)ws;                                            // 128
    unsigned* cntrs  = (unsigned*)(ws + MAXB * 4);                               // 8
    int*      cn     = (int*)(ws + (MAXB + 8) * 4);                              // cnw
    float2*   P2     = (float2*)(ws + ((size_t)cnw + MAXB + 8) * 4);             // 2n
    unsigned* isCN   = (unsigned*)(ws + ((size_t)cnw + 2 * (size_t)n_nodes
                                         + MAXB + 8) * 4);                       // nwp
    float*    rep    = (float*)((char*)isCN + (size_t)nwp * 4);
    size_t rep_w     = (size_t)NB2 * ESLICES * B2SIZE;
    char*     tail   = (char*)rep + rep_w * 4;

    size_t fixed_words = (size_t)cnw + 2 * (size_t)n_nodes + MAXB + 8
                         + nwp + rep_w;
    size_t total_words = ws_size / 4;
    size_t avail = total_words > fixed_words ? total_words - fixed_words : 0;
    size_t ovw = avail / 64;                      // ~1.5% to overflow queue
    unsigned ocap = (unsigned)(ovw / 4);          // uint4 records
    size_t capw = (avail - ovw) / (size_t)NB2;    // words per bucket
    long cap = (long)((capw / 2) & ~(size_t)3);   // uint2 records, 4-rec aligned
    if (cap > n_edges) cap = (n_edges + 3) & ~3;
    if (cap < 0) cap = 0;
    uint4* ovrec   = (uint4*)tail;
    uint2* buckets = (uint2*)(tail + (size_t)ocap * 16);

    const int B = 256;
    int node_blocks = (n_nodes + B - 1) / B;
    int scat_blocks = (n_edges + TILE - 1) / TILE;
    int nunits      = NB2 * ESLICES;
    int zero_words  = cnw + MAXB + 8;             // cursor + cntrs + cn
    int zq = zero_words / 4;

    gnb_init<<<256, B, 0, stream>>>(Z, isCN, nw, n_nodes, (int4*)ws, zq,
                                    (int*)ws, zero_words);
    gnb_scatter<<<scat_blocks, SBLK, 0, stream>>>(send, recv, len, isCN, cn,
                                                  buckets, cursor, ovrec, cntrs,
                                                  n_edges, (unsigned)cap, ocap);
    gnb_params<<<node_blocks, B, 0, stream>>>(Z, cn, P2, n_nodes);
    gnb_accum<<<nunits, BLK, 0, stream>>>(buckets, cursor, ovrec, cntrs,
                                          P2, rep, (unsigned)cap, ocap, n_nodes);
    gnb_reduce<<<node_blocks, B, 0, stream>>>(rep, out, n_nodes);
}